// Round 15
// baseline (256.013 us; speedup 1.0000x reference)
//
#include <hip/hip_runtime.h>
#include <math.h>

#define N_NODES 100000
#define E_EDGES 1600000
#define HALF_E  (E_EDGES / 2)

#define NBUCK 256
#define ROWS_PER_BUCKET ((N_NODES + NBUCK - 1) / NBUCK)   // 391
#define EDGES_PER_BLK_A 4096
#define NBLK_A ((E_EDGES + EDGES_PER_BLK_A - 1) / EDGES_PER_BLK_A)  // 391
#define NBH_BLOCKS 256

typedef unsigned short ushort_t;
typedef unsigned int uint_t;
typedef __attribute__((ext_vector_type(8))) short bf16x8;
typedef __attribute__((ext_vector_type(8))) unsigned short u16x8;
typedef __attribute__((ext_vector_type(4))) float f32x4;

#define MFMA16(a, b, c) __builtin_amdgcn_mfma_f32_16x16x32_bf16(a, b, c, 0, 0, 0)

// ---- bf16 helpers (RNE pack, cheap unpack) ----
__device__ __forceinline__ unsigned bf16_1(float f) {
    unsigned u = __float_as_uint(f);
    return (u + 0x7fffu + ((u >> 16) & 1u)) >> 16;
}
__device__ __forceinline__ float bf16_f(ushort_t us) {
    return __uint_as_float(((unsigned)us) << 16);
}

// ============ CSR build (bucketed; pairs packed: (localRow<<17)|col) ============

__global__ __launch_bounds__(256) void k_bhist(const int* __restrict__ rowIdx,
                                               int* __restrict__ part) {
    __shared__ int c[NBUCK];
    const int tid = threadIdx.x;
    c[tid] = 0;
    __syncthreads();
    for (int e = blockIdx.x * 256 + tid; e < E_EDGES; e += NBH_BLOCKS * 256)
        atomicAdd(&c[rowIdx[e] / ROWS_PER_BUCKET], 1);
    __syncthreads();
    part[blockIdx.x * NBUCK + tid] = c[tid];
}

__global__ __launch_bounds__(256) void k_bscan256(const int* __restrict__ part,
                                                  int* __restrict__ bbase,
                                                  int* __restrict__ curA,
                                                  int* __restrict__ start) {
    __shared__ int sc[NBUCK];
    const int tid = threadIdx.x;
    int v = 0;
    for (int b = 0; b < NBH_BLOCKS; ++b) v += part[b * NBUCK + tid];
    sc[tid] = v;
    __syncthreads();
    for (int st = 1; st < 256; st <<= 1) {
        int t = (tid >= st) ? sc[tid - st] : 0;
        __syncthreads();
        sc[tid] += t;
        __syncthreads();
    }
    int excl = sc[tid] - v;
    bbase[tid] = excl;
    curA[tid] = excl;
    if (tid == 255) bbase[256] = sc[255];
    if (tid == 0) start[N_NODES] = E_EDGES;
}

__global__ __launch_bounds__(256) void k_bucketA(const int* __restrict__ rowIdx,
                                                 const int* __restrict__ colIdx,
                                                 int* __restrict__ cursorA,
                                                 uint_t* __restrict__ pairs) {
    __shared__ uint_t stage[EDGES_PER_BLK_A];
    __shared__ unsigned char bmap[EDGES_PER_BLK_A];
    __shared__ int cntL[NBUCK], scanEx[NBUCK], cur[NBUCK], posG[NBUCK];
    const int tid = threadIdx.x;
    const int e0 = blockIdx.x * EDGES_PER_BLK_A;
    const int n = min(EDGES_PER_BLK_A, E_EDGES - e0);

    cntL[tid] = 0;
    __syncthreads();
    for (int i = tid; i < n; i += 256) {
        int b = rowIdx[e0 + i] / ROWS_PER_BUCKET;
        atomicAdd(&cntL[b], 1);
    }
    __syncthreads();
    int myc = cntL[tid];
    scanEx[tid] = myc;
    __syncthreads();
    for (int st = 1; st < 256; st <<= 1) {
        int t = (tid >= st) ? scanEx[tid - st] : 0;
        __syncthreads();
        scanEx[tid] += t;
        __syncthreads();
    }
    int ex = scanEx[tid] - myc;
    __syncthreads();
    scanEx[tid] = ex;
    cur[tid] = ex;
    if (myc) posG[tid] = atomicAdd(&cursorA[tid], myc);
    __syncthreads();
    for (int i = tid; i < n; i += 256) {
        int r = rowIdx[e0 + i];
        int c = colIdx[e0 + i];
        int b = r / ROWS_PER_BUCKET;
        int lr = r - b * ROWS_PER_BUCKET;
        int slot = atomicAdd(&cur[b], 1);
        stage[slot] = ((uint_t)lr << 17) | (uint_t)c;
        bmap[slot] = (unsigned char)b;
    }
    __syncthreads();
    for (int i = tid; i < n; i += 256) {
        int b = bmap[i];
        int dst = posG[b] + (i - scanEx[b]);
        pairs[dst] = stage[i];
    }
}

__global__ __launch_bounds__(256) void k_bucketB(const int* __restrict__ bbase,
                                                 const uint_t* __restrict__ pairs,
                                                 int* __restrict__ start,
                                                 int* __restrict__ csr) {
    __shared__ int cur[ROWS_PER_BUCKET];
    __shared__ int scn[512];
    const int tid = threadIdx.x;
    const int rowbase = blockIdx.x * ROWS_PER_BUCKET;
    const int nrows = min(ROWS_PER_BUCKET, N_NODES - rowbase);
    for (int i = tid; i < nrows; i += 256) cur[i] = 0;
    __syncthreads();
    const int bBeg = bbase[blockIdx.x];
    const int bEnd = bbase[blockIdx.x + 1];
    for (int i = bBeg + tid; i < bEnd; i += 256)
        atomicAdd(&cur[pairs[i] >> 17], 1);
    __syncthreads();
    scn[tid] = (tid < nrows) ? cur[tid] : 0;
    scn[tid + 256] = (tid + 256 < nrows) ? cur[tid + 256] : 0;
    __syncthreads();
    for (int st = 1; st < 512; st <<= 1) {
        int i0 = tid, i1 = tid + 256;
        int t0 = (i0 >= st) ? scn[i0 - st] : 0;
        int t1 = (i1 >= st) ? scn[i1 - st] : 0;
        __syncthreads();
        scn[i0] += t0;
        scn[i1] += t1;
        __syncthreads();
    }
    for (int i = tid; i < nrows; i += 256) {
        int sv = bBeg + scn[i] - cur[i];
        start[rowbase + i] = sv;
        cur[i] = sv;
    }
    __syncthreads();
    for (int i = bBeg + tid; i < bEnd; i += 256) {
        uint_t p = pairs[i];
        int pos = atomicAdd(&cur[p >> 17], 1);
        csr[pos] = (int)(p & 0x1FFFFu);
    }
}

// ============ weight split (fp32 -> fragment-layout bf16 hi/lo) ============
__global__ __launch_bounds__(512) void k_wsplit(const float* __restrict__ w_in,
                                                const float* __restrict__ l0_m1w,
                                                const float* __restrict__ l0_m2w,
                                                const float* __restrict__ l0_u1w,
                                                const float* __restrict__ l0_u2w,
                                                const float* __restrict__ l1_m1w,
                                                const float* __restrict__ l1_m2w,
                                                const float* __restrict__ l1_u1w,
                                                const float* __restrict__ l1_u2w,
                                                const float* __restrict__ h1w,
                                                ushort_t* __restrict__ whi,
                                                ushort_t* __restrict__ wlo) {
    const float* src;
    switch (blockIdx.x) {
        case 0:  src = w_in;           break;
        case 1:  src = w_in + 4096;    break;
        case 2:  src = l0_m1w;         break;
        case 3:  src = l0_m2w;         break;
        case 4:  src = l0_u1w;         break;
        case 5:  src = l0_u1w + 4096;  break;
        case 6:  src = l0_u2w;         break;
        case 7:  src = l1_m1w;         break;
        case 8:  src = l1_m2w;         break;
        case 9:  src = l1_u1w;         break;
        case 10: src = l1_u1w + 4096;  break;
        case 11: src = l1_u2w;         break;
        case 12: src = h1w;            break;
        default: src = h1w + 4096;     break;
    }
    const int tid = threadIdx.x;
    const int h = tid >> 8;
    const int c = (tid >> 6) & 3;
    const int lane = tid & 63;
    const int kg = lane >> 4, lr = lane & 15;
    const int col = c * 16 + lr;
    u16x8 hi8, lo8;
#pragma unroll
    for (int j = 0; j < 8; ++j) {
        int k = h * 32 + kg * 8 + j;
        float v = src[k * 64 + col];
        unsigned uh = bf16_1(v);
        hi8[j] = (unsigned short)uh;
        lo8[j] = (unsigned short)bf16_1(v - __uint_as_float(uh << 16));
    }
    size_t idx = (size_t)blockIdx.x * 4096 + ((size_t)(h * 4 + c) * 64 + lane) * 8;
    *(u16x8*)(whi + idx) = hi8;
    *(u16x8*)(wlo + idx) = lo8;
}

// ============ MFMA node-MLP machinery ============

__device__ __forceinline__ void mfma_gemm64(const ushort_t* Shi, const ushort_t* Slo,
                                            const ushort_t* __restrict__ whi,
                                            const ushort_t* __restrict__ wlo,
                                            int panel, int lane, int q, f32x4 acc[4]) {
    const ushort_t* WH = whi + (size_t)panel * 4096;
    const ushort_t* WL = wlo + (size_t)panel * 4096;
    const int f0 = (q * 64 + lane) * 8;
    const int f1 = ((4 + q) * 64 + lane) * 8;
    bf16x8 bh0 = *(const bf16x8*)(WH + f0);
    bf16x8 bh1 = *(const bf16x8*)(WH + f1);
    bf16x8 bl0 = *(const bf16x8*)(WL + f0);
    bf16x8 bl1 = *(const bf16x8*)(WL + f1);
    const int ar = (lane & 15) * 72 + ((lane >> 4) << 3);
#pragma unroll
    for (int t = 0; t < 4; ++t) {
        const ushort_t* a  = Shi + t * 16 * 72 + ar;
        const ushort_t* al = Slo + t * 16 * 72 + ar;
        bf16x8 ah0 = *(const bf16x8*)(a);
        bf16x8 ah1 = *(const bf16x8*)(a + 32);
        bf16x8 aL0 = *(const bf16x8*)(al);
        bf16x8 aL1 = *(const bf16x8*)(al + 32);
        acc[t] = MFMA16(ah0, bh0, acc[t]);
        acc[t] = MFMA16(ah1, bh1, acc[t]);
        acc[t] = MFMA16(ah0, bl0, acc[t]);
        acc[t] = MFMA16(aL0, bh0, acc[t]);
        acc[t] = MFMA16(ah1, bl1, acc[t]);
        acc[t] = MFMA16(aL1, bh1, acc[t]);
    }
}

__device__ __forceinline__ void load16(const float* src, bool valid, float scale,
                                       float v[16]) {
#pragma unroll
    for (int j4 = 0; j4 < 4; ++j4) {
        float4 t = valid ? *(const float4*)(src + j4 * 4) : make_float4(0.f, 0.f, 0.f, 0.f);
        v[j4 * 4 + 0] = t.x * scale;
        v[j4 * 4 + 1] = t.y * scale;
        v[j4 * 4 + 2] = t.z * scale;
        v[j4 * 4 + 3] = t.w * scale;
    }
}

__device__ __forceinline__ void split16_store(ushort_t* Shi, ushort_t* Slo,
                                              int row, int c0, const float v[16]) {
    u16x8 ha, la, hb, lb;
#pragma unroll
    for (int j = 0; j < 8; ++j) {
        unsigned uh = bf16_1(v[j]);
        ha[j] = (unsigned short)uh;
        la[j] = (unsigned short)bf16_1(v[j] - __uint_as_float(uh << 16));
    }
#pragma unroll
    for (int j = 0; j < 8; ++j) {
        unsigned uh = bf16_1(v[8 + j]);
        hb[j] = (unsigned short)uh;
        lb[j] = (unsigned short)bf16_1(v[8 + j] - __uint_as_float(uh << 16));
    }
    *(u16x8*)(Shi + row * 72 + c0) = ha;
    *(u16x8*)(Shi + row * 72 + c0 + 8) = hb;
    *(u16x8*)(Slo + row * 72 + c0) = la;
    *(u16x8*)(Slo + row * 72 + c0 + 8) = lb;
}

__device__ __forceinline__ void epi_S(const f32x4 acc[4], bool relu,
                                      ushort_t* Shi, ushort_t* Slo,
                                      int lane, int colL) {
#pragma unroll
    for (int t = 0; t < 4; ++t)
#pragma unroll
        for (int i = 0; i < 4; ++i) {
            int row = t * 16 + ((lane >> 4) << 2) + i;
            float vv = acc[t][i];
            if (relu) vv = fmaxf(vv, 0.f);
            unsigned uh = bf16_1(vv);
            Shi[row * 72 + colL] = (ushort_t)uh;
            Slo[row * 72 + colL] = (ushort_t)bf16_1(vv - __uint_as_float(uh << 16));
        }
}

// h = x@w_in+b_in ; msg16 = relu(relu(h@m1+b1)@m2+b2)
__global__ __launch_bounds__(256, 4) void k_lin_msg(const float* __restrict__ x,
                                                    const ushort_t* __restrict__ whi,
                                                    const ushort_t* __restrict__ wlo,
                                                    const float* __restrict__ b_in,
                                                    const float* __restrict__ m1b,
                                                    const float* __restrict__ m2b,
                                                    float* __restrict__ h,
                                                    ushort_t* __restrict__ msg16) {
    __shared__ ushort_t Shi[64 * 72];
    __shared__ ushort_t Slo[64 * 72];
    const int tid = threadIdx.x;
    const int lane = tid & 63;
    const int q = __builtin_amdgcn_readfirstlane(tid >> 6);
    const int colL = q * 16 + (lane & 15);
    const int r0 = blockIdx.x * 64;
    const int nrows = min(64, N_NODES - r0);
    const int srow = tid >> 2, c0 = (tid & 3) * 16;
    const bool rv = srow < nrows;

    f32x4 acc[4];
    {
        float bj = b_in[colL];
#pragma unroll
        for (int t = 0; t < 4; ++t) acc[t] = (f32x4){bj, bj, bj, bj};
    }
    float v[16];
    load16(x + (size_t)(r0 + srow) * 128 + c0, rv, 1.f, v);
    split16_store(Shi, Slo, srow, c0, v);
    __syncthreads();
    mfma_gemm64(Shi, Slo, whi, wlo, 0, lane, q, acc);
    __syncthreads();
    load16(x + (size_t)(r0 + srow) * 128 + 64 + c0, rv, 1.f, v);
    split16_store(Shi, Slo, srow, c0, v);
    __syncthreads();
    mfma_gemm64(Shi, Slo, whi, wlo, 1, lane, q, acc);
    __syncthreads();
#pragma unroll
    for (int t = 0; t < 4; ++t)
#pragma unroll
        for (int i = 0; i < 4; ++i) {
            int row = t * 16 + ((lane >> 4) << 2) + i;
            int grow = r0 + row;
            if (grow < N_NODES) h[(size_t)grow * 64 + colL] = acc[t][i];
        }
    epi_S(acc, false, Shi, Slo, lane, colL);
    __syncthreads();

    {
        float bj = m1b[colL];
#pragma unroll
        for (int t = 0; t < 4; ++t) acc[t] = (f32x4){bj, bj, bj, bj};
    }
    mfma_gemm64(Shi, Slo, whi, wlo, 2, lane, q, acc);
    __syncthreads();
    epi_S(acc, true, Shi, Slo, lane, colL);
    __syncthreads();

    {
        float bj = m2b[colL];
#pragma unroll
        for (int t = 0; t < 4; ++t) acc[t] = (f32x4){bj, bj, bj, bj};
    }
    mfma_gemm64(Shi, Slo, whi, wlo, 3, lane, q, acc);
#pragma unroll
    for (int t = 0; t < 4; ++t)
#pragma unroll
        for (int i = 0; i < 4; ++i) {
            int row = t * 16 + ((lane >> 4) << 2) + i;
            int grow = r0 + row;
            if (grow < N_NODES)
                msg16[(size_t)grow * 64 + colL] = (ushort_t)bf16_1(fmaxf(acc[t][i], 0.f));
        }
}

// ============ aggregation: gather, 8 edges per VMEM instruction ============
__global__ __launch_bounds__(256) void k_gather(const int* __restrict__ start,
                                                const int* __restrict__ csr,
                                                const ushort_t* __restrict__ msg16,
                                                float* __restrict__ agg) {
    const int lane = threadIdx.x & 63;
    const int wid  = threadIdx.x >> 6;
    const int g8   = lane >> 3;
    const int s8   = lane & 7;
    int r = blockIdx.x * 4 + wid;
    if (r >= N_NODES) return;
    int b = start[r];
    int e0 = start[r + 1];
    float a[8] = {0.f, 0.f, 0.f, 0.f, 0.f, 0.f, 0.f, 0.f};
    for (int base = b; base < e0; base += 64) {
        int n = e0 - base;
        if (n > 64) n = 64;
        int c = 0;
        if (base + lane < e0) c = csr[base + lane];
        for (int j = 0; j < n; j += 8) {
            int jj = j + g8;
            bool act = jj < n;
            int cj = __shfl(c, act ? jj : 0, 64);
            u16x8 v = *(const u16x8*)(msg16 + (size_t)cj * 64 + s8 * 8);
            if (act) {
#pragma unroll
                for (int k = 0; k < 8; ++k) a[k] += bf16_f((ushort_t)v[k]);
            }
        }
    }
#pragma unroll
    for (int k = 0; k < 8; ++k) {
        a[k] += __shfl_xor(a[k], 8, 64);
        a[k] += __shfl_xor(a[k], 16, 64);
        a[k] += __shfl_xor(a[k], 32, 64);
    }
    if (g8 == 0) {
        float* dst = agg + (size_t)r * 64 + s8 * 8;
        *(float4*)(dst)     = make_float4(a[0], a[1], a[2], a[3]);
        *(float4*)(dst + 4) = make_float4(a[4], a[5], a[6], a[7]);
    }
}

// ---- update layer0 then msg layer1 (MFMA) ----
__global__ __launch_bounds__(256, 4) void k_update_msg(float* __restrict__ h,
                                                       const float* __restrict__ agg,
                                                       const int* __restrict__ start,
                                                       const ushort_t* __restrict__ whi,
                                                       const ushort_t* __restrict__ wlo,
                                                       const float* __restrict__ b1,
                                                       const float* __restrict__ b2,
                                                       const float* __restrict__ m1b,
                                                       const float* __restrict__ m2b,
                                                       ushort_t* __restrict__ msg16) {
    __shared__ ushort_t Shi[64 * 72];
    __shared__ ushort_t Slo[64 * 72];
    const int tid = threadIdx.x;
    const int lane = tid & 63;
    const int q = __builtin_amdgcn_readfirstlane(tid >> 6);
    const int colL = q * 16 + (lane & 15);
    const int r0 = blockIdx.x * 64;
    const int nrows = min(64, N_NODES - r0);
    const int srow = tid >> 2, c0 = (tid & 3) * 16;
    const bool rv = srow < nrows;

    f32x4 acc[4];
    {
        float bj = b1[colL];
#pragma unroll
        for (int t = 0; t < 4; ++t) acc[t] = (f32x4){bj, bj, bj, bj};
    }
    float v[16];
    {
        float invS = 0.f;
        if (rv) {
            int g = r0 + srow;
            invS = 1.f / fmaxf((float)(start[g + 1] - start[g]), 1.f);
        }
        load16(agg + (size_t)(r0 + srow) * 64 + c0, rv, invS, v);
        split16_store(Shi, Slo, srow, c0, v);
    }
    __syncthreads();
    mfma_gemm64(Shi, Slo, whi, wlo, 5, lane, q, acc);
    __syncthreads();
    load16(h + (size_t)(r0 + srow) * 64 + c0, rv, 1.f, v);
    split16_store(Shi, Slo, srow, c0, v);
    __syncthreads();
    mfma_gemm64(Shi, Slo, whi, wlo, 4, lane, q, acc);
    float res[16];
#pragma unroll
    for (int t = 0; t < 4; ++t)
#pragma unroll
        for (int i = 0; i < 4; ++i) {
            int row = t * 16 + ((lane >> 4) << 2) + i;
            res[t * 4 + i] = bf16_f(Shi[row * 72 + colL]) + bf16_f(Slo[row * 72 + colL]);
        }
    __syncthreads();
    epi_S(acc, true, Shi, Slo, lane, colL);
    __syncthreads();

    {
        float bj = b2[colL];
#pragma unroll
        for (int t = 0; t < 4; ++t) acc[t] = (f32x4){bj, bj, bj, bj};
    }
    mfma_gemm64(Shi, Slo, whi, wlo, 6, lane, q, acc);
    __syncthreads();
#pragma unroll
    for (int t = 0; t < 4; ++t)
#pragma unroll
        for (int i = 0; i < 4; ++i) {
            int row = t * 16 + ((lane >> 4) << 2) + i;
            float vv = acc[t][i] + res[t * 4 + i];
            int grow = r0 + row;
            if (grow < N_NODES) h[(size_t)grow * 64 + colL] = vv;
            unsigned uh = bf16_1(vv);
            Shi[row * 72 + colL] = (ushort_t)uh;
            Slo[row * 72 + colL] = (ushort_t)bf16_1(vv - __uint_as_float(uh << 16));
        }
    __syncthreads();

    {
        float bj = m1b[colL];
#pragma unroll
        for (int t = 0; t < 4; ++t) acc[t] = (f32x4){bj, bj, bj, bj};
    }
    mfma_gemm64(Shi, Slo, whi, wlo, 7, lane, q, acc);
    __syncthreads();
    epi_S(acc, true, Shi, Slo, lane, colL);
    __syncthreads();

    {
        float bj = m2b[colL];
#pragma unroll
        for (int t = 0; t < 4; ++t) acc[t] = (f32x4){bj, bj, bj, bj};
    }
    mfma_gemm64(Shi, Slo, whi, wlo, 8, lane, q, acc);
#pragma unroll
    for (int t = 0; t < 4; ++t)
#pragma unroll
        for (int i = 0; i < 4; ++i) {
            int row = t * 16 + ((lane >> 4) << 2) + i;
            int grow = r0 + row;
            if (grow < N_NODES)
                msg16[(size_t)grow * 64 + colL] = (ushort_t)bf16_1(fmaxf(acc[t][i], 0.f));
        }
}

// ---- update layer1 then head precompute (MFMA) ----
__global__ __launch_bounds__(256, 4) void k_update_headpre(const float* __restrict__ h,
                                                           const float* __restrict__ agg,
                                                           const int* __restrict__ start,
                                                           const ushort_t* __restrict__ whi,
                                                           const ushort_t* __restrict__ wlo,
                                                           const float* __restrict__ b1,
                                                           const float* __restrict__ b2,
                                                           const float* __restrict__ h1w,
                                                           const float* __restrict__ hb1,
                                                           ushort_t* __restrict__ hA16,
                                                           ushort_t* __restrict__ hB16) {
    __shared__ ushort_t Shi[64 * 72];
    __shared__ ushort_t Slo[64 * 72];
    __shared__ float degS[64];
    const int tid = threadIdx.x;
    const int lane = tid & 63;
    const int q = __builtin_amdgcn_readfirstlane(tid >> 6);
    const int colL = q * 16 + (lane & 15);
    const int r0 = blockIdx.x * 64;
    const int nrows = min(64, N_NODES - r0);
    const int srow = tid >> 2, c0 = (tid & 3) * 16;
    const bool rv = srow < nrows;

    if (tid < 64) {
        int g = r0 + tid;
        degS[tid] = (g < N_NODES) ? (float)(start[g + 1] - start[g]) : 0.f;
    }
    __syncthreads();

    f32x4 acc[4];
    {
        float bj = b1[colL];
#pragma unroll
        for (int t = 0; t < 4; ++t) acc[t] = (f32x4){bj, bj, bj, bj};
    }
    float v[16];
    {
        float invS = rv ? (1.f / fmaxf(degS[srow], 1.f)) : 0.f;
        load16(agg + (size_t)(r0 + srow) * 64 + c0, rv, invS, v);
        split16_store(Shi, Slo, srow, c0, v);
    }
    __syncthreads();
    mfma_gemm64(Shi, Slo, whi, wlo, 10, lane, q, acc);
    __syncthreads();
    load16(h + (size_t)(r0 + srow) * 64 + c0, rv, 1.f, v);
    split16_store(Shi, Slo, srow, c0, v);
    __syncthreads();
    mfma_gemm64(Shi, Slo, whi, wlo, 9, lane, q, acc);
    float res[16];
#pragma unroll
    for (int t = 0; t < 4; ++t)
#pragma unroll
        for (int i = 0; i < 4; ++i) {
            int row = t * 16 + ((lane >> 4) << 2) + i;
            res[t * 4 + i] = bf16_f(Shi[row * 72 + colL]) + bf16_f(Slo[row * 72 + colL]);
        }
    __syncthreads();
    epi_S(acc, true, Shi, Slo, lane, colL);
    __syncthreads();

    {
        float bj = b2[colL];
#pragma unroll
        for (int t = 0; t < 4; ++t) acc[t] = (f32x4){bj, bj, bj, bj};
    }
    mfma_gemm64(Shi, Slo, whi, wlo, 11, lane, q, acc);
    __syncthreads();
#pragma unroll
    for (int t = 0; t < 4; ++t)
#pragma unroll
        for (int i = 0; i < 4; ++i) {
            int row = t * 16 + ((lane >> 4) << 2) + i;
            float vv = acc[t][i] + res[t * 4 + i];
            unsigned uh = bf16_1(vv);
            Shi[row * 72 + colL] = (ushort_t)uh;
            Slo[row * 72 + colL] = (ushort_t)bf16_1(vv - __uint_as_float(uh << 16));
        }
    __syncthreads();

    const float hb1c  = hb1[colL];
    const float w128c = h1w[128 * 64 + colL];
    const float w129c = h1w[129 * 64 + colL];

#pragma unroll
    for (int t = 0; t < 4; ++t)
#pragma unroll
        for (int i = 0; i < 4; ++i) {
            int row = t * 16 + ((lane >> 4) << 2) + i;
            acc[t][i] = hb1c + degS[row] * w128c;
        }
    mfma_gemm64(Shi, Slo, whi, wlo, 12, lane, q, acc);
#pragma unroll
    for (int t = 0; t < 4; ++t)
#pragma unroll
        for (int i = 0; i < 4; ++i) {
            int row = t * 16 + ((lane >> 4) << 2) + i;
            int grow = r0 + row;
            if (grow < N_NODES)
                hA16[(size_t)grow * 64 + colL] = (ushort_t)bf16_1(acc[t][i]);
        }

#pragma unroll
    for (int t = 0; t < 4; ++t)
#pragma unroll
        for (int i = 0; i < 4; ++i) {
            int row = t * 16 + ((lane >> 4) << 2) + i;
            acc[t][i] = degS[row] * w129c;
        }
    mfma_gemm64(Shi, Slo, whi, wlo, 13, lane, q, acc);
#pragma unroll
    for (int t = 0; t < 4; ++t)
#pragma unroll
        for (int i = 0; i < 4; ++i) {
            int row = t * 16 + ((lane >> 4) << 2) + i;
            int grow = r0 + row;
            if (grow < N_NODES)
                hB16[(size_t)grow * 64 + colL] = (ushort_t)bf16_1(acc[t][i]);
        }
}

// ------- out[e] = out[e+HALF] = softplus(relu(hA[src]+hB[dst]) . h2w + h2b) + 1e-6 ------
__global__ __launch_bounds__(256) void k_head(const int* __restrict__ rowIdx,
                                              const int* __restrict__ colIdx,
                                              const ushort_t* __restrict__ hA16,
                                              const ushort_t* __restrict__ hB16,
                                              const float* __restrict__ w2,
                                              const float* __restrict__ b2,
                                              float* __restrict__ out) {
    const int lane = threadIdx.x & 63;
    const int sub = lane & 7;
    const int grp = lane >> 3;
    const int waveId = (blockIdx.x * 256 + threadIdx.x) >> 6;
    const int step = gridDim.x * 4 * 8;
    float w2v[8];
    {
        float4 wa = *(const float4*)(w2 + sub * 8);
        float4 wb = *(const float4*)(w2 + sub * 8 + 4);
        w2v[0] = wa.x; w2v[1] = wa.y; w2v[2] = wa.z; w2v[3] = wa.w;
        w2v[4] = wb.x; w2v[5] = wb.y; w2v[6] = wb.z; w2v[7] = wb.w;
    }
    const float b2v = b2[0];
    for (int e = waveId * 8 + grp; e < HALF_E; e += step) {
        int s = rowIdx[e];
        int d = colIdx[e];
        u16x8 a8 = *(const u16x8*)(hA16 + (size_t)s * 64 + sub * 8);
        u16x8 b8 = *(const u16x8*)(hB16 + (size_t)d * 64 + sub * 8);
        float p = 0.f;
#pragma unroll
        for (int k = 0; k < 8; ++k) {
            float t = bf16_f((ushort_t)a8[k]) + bf16_f((ushort_t)b8[k]);
            p = fmaf(fmaxf(t, 0.f), w2v[k], p);
        }
        p += __shfl_xor(p, 1);
        p += __shfl_xor(p, 2);
        p += __shfl_xor(p, 4);
        if (sub == 0) {
            float sv = p + b2v;
            float sp = fmaxf(sv, 0.0f) + log1pf(expf(-fabsf(sv)));
            float wvv = sp + 1e-6f;
            out[e] = wvv;
            out[e + HALF_E] = wvv;
        }
    }
}

extern "C" void kernel_launch(void* const* d_in, const int* in_sizes, int n_in,
                              void* d_out, int out_size, void* d_ws, size_t ws_size,
                              hipStream_t stream) {
    const float* x      = (const float*)d_in[0];
    const int*   rowIdx = (const int*)d_in[1];
    const int*   colIdx = rowIdx + E_EDGES;
    const float* w_in   = (const float*)d_in[2];
    const float* b_in   = (const float*)d_in[3];
    const float* l0_m1w = (const float*)d_in[4];
    const float* l0_m1b = (const float*)d_in[5];
    const float* l0_m2w = (const float*)d_in[6];
    const float* l0_m2b = (const float*)d_in[7];
    const float* l0_u1w = (const float*)d_in[8];
    const float* l0_u1b = (const float*)d_in[9];
    const float* l0_u2w = (const float*)d_in[10];
    const float* l0_u2b = (const float*)d_in[11];
    const float* l1_m1w = (const float*)d_in[12];
    const float* l1_m1b = (const float*)d_in[13];
    const float* l1_m2w = (const float*)d_in[14];
    const float* l1_m2b = (const float*)d_in[15];
    const float* l1_u1w = (const float*)d_in[16];
    const float* l1_u1b = (const float*)d_in[17];
    const float* l1_u2w = (const float*)d_in[18];
    const float* l1_u2b = (const float*)d_in[19];
    const float* h1w    = (const float*)d_in[20];
    const float* h1b    = (const float*)d_in[21];
    const float* h2w    = (const float*)d_in[22];
    const float* h2b    = (const float*)d_in[23];

    float* out = (float*)d_out;

    float*    h     = (float*)d_ws;                         // N x 64 f32
    float*    agg   = h + (size_t)N_NODES * 64;             // N x 64 f32
    ushort_t* msg16 = (ushort_t*)(agg + (size_t)N_NODES * 64); // N x 64 bf16
    ushort_t* hB16  = msg16 + (size_t)N_NODES * 64;         // N x 64 bf16
    int*      start = (int*)(hB16 + (size_t)N_NODES * 64);  // N + 1
    int*      part  = start + N_NODES + 1;                  // 256*256 partial hist
    int*      bbase = part + NBH_BLOCKS * NBUCK;            // 257 (pad 32)
    int*      curA  = bbase + NBUCK + 32;                   // 256
    int*      csr   = curA + NBUCK;                         // E
    ushort_t* whi   = (ushort_t*)(csr + E_EDGES);           // 14*4096 bf16
    ushort_t* wlo   = whi + 14 * 4096;                      // 14*4096 bf16
    uint_t*   pairs = (uint_t*)agg;                         // alias: dead before gather writes agg
    ushort_t* hA16  = msg16;                                // alias: msg16 dead after gather1

    const int nb64 = (N_NODES + 63) / 64;                   // 1563 blocks for MLP kernels
    const int gatherBlocks = (N_NODES + 3) / 4;

    // ---- CSR build + weight split ----
    k_bhist<<<NBH_BLOCKS, 256, 0, stream>>>(rowIdx, part);
    k_bscan256<<<1, 256, 0, stream>>>(part, bbase, curA, start);
    k_bucketA<<<NBLK_A, 256, 0, stream>>>(rowIdx, colIdx, curA, pairs);
    k_bucketB<<<NBUCK, 256, 0, stream>>>(bbase, pairs, start, csr);
    k_wsplit<<<14, 512, 0, stream>>>(w_in, l0_m1w, l0_m2w, l0_u1w, l0_u2w,
                                     l1_m1w, l1_m2w, l1_u1w, l1_u2w, h1w, whi, wlo);

    // ---- input linear + layer0 message ----
    k_lin_msg<<<nb64, 256, 0, stream>>>(x, whi, wlo, b_in, l0_m1b, l0_m2b, h, msg16);
    // ---- layer 0 ----
    k_gather<<<gatherBlocks, 256, 0, stream>>>(start, csr, msg16, agg);
    k_update_msg<<<nb64, 256, 0, stream>>>(h, agg, start, whi, wlo,
                                           l0_u1b, l0_u2b, l1_m1b, l1_m2b, msg16);
    // ---- layer 1 ----
    k_gather<<<gatherBlocks, 256, 0, stream>>>(start, csr, msg16, agg);
    k_update_headpre<<<nb64, 256, 0, stream>>>(h, agg, start, whi, wlo,
                                               l1_u1b, l1_u2b, h1w, h1b, hA16, hB16);
    // ---- head ----
    k_head<<<4096, 256, 0, stream>>>(rowIdx, colIdx, hA16, hB16, h2w, h2b, out);
}